// Round 1
// baseline (200.046 us; speedup 1.0000x reference)
//
#include <hip/hip_runtime.h>
#include <hip/hip_bf16.h>
#include <cstdint>

typedef __attribute__((ext_vector_type(8))) short bf16x8;
typedef __attribute__((ext_vector_type(4))) float f32x4;
typedef __attribute__((ext_vector_type(4))) unsigned int u32x4;
typedef __attribute__((ext_vector_type(8))) unsigned short u16x8;

#define DEV static __device__ __forceinline__

DEV unsigned short f2b(float x) {
    __hip_bfloat16 b = __float2bfloat16(x);
    return __builtin_bit_cast(unsigned short, b);
}
DEV float b2f(unsigned short u) {
    __hip_bfloat16 b = __builtin_bit_cast(__hip_bfloat16, u);
    return __bfloat162float(b);
}

// ---------------------------------------------------------------------------
// prep: fold BN into weights, transpose to [N][K]; q-scale folded into q cols
// ---------------------------------------------------------------------------
__global__ void prep_w_qkv(const float* __restrict__ w, const float* __restrict__ g,
                           const float* __restrict__ be, const float* __restrict__ mu,
                           const float* __restrict__ va, unsigned short* __restrict__ wT,
                           float* __restrict__ t1)
{
    int gid = blockIdx.x * 256 + threadIdx.x;   // 384*1024 threads
    int c = gid & 1023, k = gid >> 10;
    float s = g[c] * rsqrtf(va[c] + 1e-5f);
    float qs = ((c & 127) < 32) ? 0.17677669529663687f : 1.0f; // fold SCALE into q
    float val = w[(size_t)k * 1024 + c] * s * qs;
    wT[(size_t)c * 384 + k] = f2b(val);
    if (k == 0) t1[c] = (be[c] - mu[c] * s) * qs;
}

// proj weights: hi/lo split, augmented K' = [hi | lo | hi] (pairs with O = [hi|hi|lo])
__global__ void prep_w_proj(const float* __restrict__ w, const float* __restrict__ g,
                            const float* __restrict__ be, const float* __restrict__ mu,
                            const float* __restrict__ va, unsigned short* __restrict__ wT,
                            float* __restrict__ t2)
{
    int gid = blockIdx.x * 256 + threadIdx.x;   // 512*384 threads
    int c = gid % 384, k = gid / 384;
    float s = g[c] * rsqrtf(va[c] + 1e-5f);
    float val = w[(size_t)k * 384 + c] * s;
    unsigned short hi = f2b(val);
    unsigned short lo = f2b(val - b2f(hi));
    size_t base = (size_t)c * 1536;
    wT[base + k]        = hi;
    wT[base + 512 + k]  = lo;
    wT[base + 1024 + k] = hi;
    if (k == 0) t2[c] = be[c] - mu[c] * s;
}

__global__ void prep_x(const float* __restrict__ x, unsigned short* __restrict__ xb)
{
    int gid = blockIdx.x * 256 + threadIdx.x;   // 16384*384
    xb[gid] = f2b(x[gid]);
}

// ---------------------------------------------------------------------------
// GEMM: C[M,N] = A[M,K] * Bt[N,K]^T (+tvec[col]).  2-barrier loop, reg staging.
// EPI=0: scatter to q/k/v bf16.  EPI=1: fp32 out (proj).
// ---------------------------------------------------------------------------
template<int BM, int BN, int EPI>
__launch_bounds__(256, 2)
__global__ void gemm_bt(const unsigned short* __restrict__ A,
                        const unsigned short* __restrict__ Bt,
                        int Kdim,
                        const float* __restrict__ tvec,
                        unsigned short* __restrict__ outq,
                        unsigned short* __restrict__ outk,
                        unsigned short* __restrict__ outv,
                        float* __restrict__ outf)
{
    constexpr int BK = 64;
    constexpr int WM = BM / 2, WN = BN / 2;
    constexpr int MI = WM / 16, NI = WN / 16;
    constexpr int RA = BM * BK / 2048;   // 16B loads per thread for A tile
    constexpr int RB = BN * BK / 2048;

    __shared__ __align__(16) unsigned short As[BM * BK];
    __shared__ __align__(16) unsigned short Bs[BN * BK];

    const int tid = threadIdx.x;
    const int lane = tid & 63, w = tid >> 6;
    const int l15 = lane & 15, lg = lane >> 4;
    const int wr = w >> 1, wc = w & 1;
    const int m0 = blockIdx.x * BM;
    const int n0 = blockIdx.y * BN;

    f32x4 acc[MI][NI];
    #pragma unroll
    for (int i = 0; i < MI; ++i)
        #pragma unroll
        for (int j = 0; j < NI; ++j) acc[i][j] = (f32x4){0.f, 0.f, 0.f, 0.f};

    u32x4 ra[RA], rb[RB];
    const int nk = Kdim / BK;

    auto load_tiles = [&](int k0) {
        #pragma unroll
        for (int i = 0; i < RA; ++i) {
            int off = (i * 256 + tid) * 8;
            int row = off >> 6, col = off & 63;
            ra[i] = *(const u32x4*)(A + (size_t)(m0 + row) * Kdim + k0 + col);
        }
        #pragma unroll
        for (int i = 0; i < RB; ++i) {
            int off = (i * 256 + tid) * 8;
            int row = off >> 6, col = off & 63;
            rb[i] = *(const u32x4*)(Bt + (size_t)(n0 + row) * Kdim + k0 + col);
        }
    };

    load_tiles(0);
    for (int kb = 0; kb < nk; ++kb) {
        __syncthreads();
        #pragma unroll
        for (int i = 0; i < RA; ++i) *(u32x4*)(&As[(i * 256 + tid) * 8]) = ra[i];
        #pragma unroll
        for (int i = 0; i < RB; ++i) *(u32x4*)(&Bs[(i * 256 + tid) * 8]) = rb[i];
        __syncthreads();
        if (kb + 1 < nk) load_tiles((kb + 1) * BK);   // prefetch next tile
        #pragma unroll
        for (int ks = 0; ks < 2; ++ks) {
            bf16x8 af[MI], bfr[NI];
            #pragma unroll
            for (int mi = 0; mi < MI; ++mi)
                af[mi] = *(const bf16x8*)(&As[(wr * WM + mi * 16 + l15) * 64 + ks * 32 + lg * 8]);
            #pragma unroll
            for (int ni = 0; ni < NI; ++ni)
                bfr[ni] = *(const bf16x8*)(&Bs[(wc * WN + ni * 16 + l15) * 64 + ks * 32 + lg * 8]);
            #pragma unroll
            for (int mi = 0; mi < MI; ++mi)
                #pragma unroll
                for (int ni = 0; ni < NI; ++ni)
                    acc[mi][ni] = __builtin_amdgcn_mfma_f32_16x16x32_bf16(
                        af[mi], bfr[ni], acc[mi][ni], 0, 0, 0);
        }
    }

    #pragma unroll
    for (int mi = 0; mi < MI; ++mi)
    #pragma unroll
    for (int ni = 0; ni < NI; ++ni)
    #pragma unroll
    for (int j = 0; j < 4; ++j) {
        int row = m0 + wr * WM + mi * 16 + lg * 4 + j;   // C/D: row=(lane>>4)*4+reg
        int col = n0 + wc * WN + ni * 16 + l15;          //      col=lane&15
        float val = acc[mi][ni][j] + tvec[col];
        if constexpr (EPI == 0) {
            int bb = row >> 10, n = row & 1023;
            int hh = col >> 7, t = col & 127;
            size_t base = (size_t)(bb * 8 + hh) * 1024 + n;
            unsigned short bv = f2b(val);
            if (t < 32)       outq[base * 32 + t] = bv;
            else if (t < 64)  outk[base * 32 + (t - 32)] = bv;
            else              outv[base * 64 + (t - 64)] = bv;
        } else {
            outf[(size_t)row * 384 + col] = val;
        }
    }
}

// ---------------------------------------------------------------------------
// v[bh][n][64] -> vt[bh][64][n]  (LDS tile transpose, coalesced both sides)
// ---------------------------------------------------------------------------
__global__ void vtrans_kernel(const unsigned short* __restrict__ v,
                              unsigned short* __restrict__ vt)
{
    __shared__ __align__(16) unsigned short tile[64][80];
    int bh = blockIdx.x, nb = blockIdx.y, t = threadIdx.x;
    #pragma unroll
    for (int rep = 0; rep < 2; ++rep) {
        int nl = (t >> 3) + rep * 32;
        int c0 = (t & 7) * 8;
        *(u32x4*)(&tile[nl][c0]) =
            *(const u32x4*)(v + ((size_t)bh * 1024 + nb * 64 + nl) * 64 + c0);
    }
    __syncthreads();
    #pragma unroll
    for (int rep = 0; rep < 2; ++rep) {
        int vd = (t >> 3) + rep * 32;
        int n0 = (t & 7) * 8;
        u16x8 o;
        #pragma unroll
        for (int i = 0; i < 8; ++i) o[i] = tile[n0 + i][vd];
        *(u16x8*)(vt + ((size_t)bh * 64 + vd) * 1024 + nb * 64 + n0) = o;
    }
}

// ---------------------------------------------------------------------------
// fused flash attention: wg = (qblk64, h, b), 4 waves x 16 q-rows.
// logits = q.k (SCALE pre-folded) + bias[h][|xi-xj|*32+|yi-yj|]; online softmax;
// epilogue: /lsum, hardswish, hi/lo split -> Oaug[tok][1536]
// ---------------------------------------------------------------------------
__launch_bounds__(256, 4)
__global__ void attn_kernel(const unsigned short* __restrict__ q,
                            const unsigned short* __restrict__ kmat,
                            const unsigned short* __restrict__ vt,
                            const float* __restrict__ ab,
                            unsigned short* __restrict__ Oaug)
{
    __shared__ __align__(16) unsigned short Vls[64 * 64];   // swizzled [vd][key]
    __shared__ __align__(16) unsigned short Pls[4 * 16 * 64]; // per-wave P
    __shared__ float biasrow[1024];

    const int tid = threadIdx.x;
    const int lane = tid & 63, w = tid >> 6;
    const int l15 = lane & 15, lg = lane >> 4;
    const int qb = blockIdx.x, h = blockIdx.y, b = blockIdx.z;
    const int bh = b * 8 + h;
    const f32x4 fzero = {0.f, 0.f, 0.f, 0.f};

    for (int i = tid; i < 1024; i += 256) biasrow[i] = ab[h * 1024 + i];

    // Q A-frag (A: row=lane&15, k=(lane>>4)*8+i) — resident whole kernel
    const int qrowA = qb * 64 + w * 16 + l15;
    const bf16x8 aq = *(const bf16x8*)(q + ((size_t)bh * 1024 + qrowA) * 32 + lg * 8);

    int xi[4], yi[4];
    #pragma unroll
    for (int j = 0; j < 4; ++j) {
        int qi = qb * 64 + w * 16 + lg * 4 + j;   // D-layout rows
        xi[j] = qi >> 5; yi[j] = qi & 31;
    }

    float m[4], lsum[4];
    f32x4 acc[4];
    #pragma unroll
    for (int j = 0; j < 4; ++j) { m[j] = -1e30f; lsum[j] = 0.f; }
    #pragma unroll
    for (int cf = 0; cf < 4; ++cf) acc[cf] = fzero;

    const int svd = tid >> 2, skq = tid & 3;
    const unsigned short* vsrc = vt + ((size_t)bh * 64 + svd) * 1024 + skq * 16;
    const int sbase = svd * 128;
    const int sxor = (svd & 7) << 4;

    for (int kb = 0; kb < 16; ++kb) {
        // stage V^T tile (issue global loads early, write after barrier)
        u32x4 d0 = *(const u32x4*)(vsrc + kb * 64);
        u32x4 d1 = *(const u32x4*)(vsrc + kb * 64 + 8);
        __syncthreads();   // prev PV done with Vls
        *(u32x4*)((char*)Vls + sbase + ((skq * 32) ^ sxor)) = d0;
        *(u32x4*)((char*)Vls + sbase + ((skq * 32 + 16) ^ sxor)) = d1;
        __syncthreads();

        // QK^T: B-frag (col=lane&15=key, k=d) straight from global k
        f32x4 s[4];
        #pragma unroll
        for (int cf = 0; cf < 4; ++cf) {
            const bf16x8 bk = *(const bf16x8*)(
                kmat + ((size_t)bh * 1024 + kb * 64 + cf * 16 + l15) * 32 + lg * 8);
            s[cf] = __builtin_amdgcn_mfma_f32_16x16x32_bf16(aq, bk, fzero, 0, 0, 0);
        }

        // bias (arithmetic rel-pos index) + online softmax
        float p[4][4];
        #pragma unroll
        for (int cf = 0; cf < 4; ++cf) {
            int ko = cf * 16 + l15;
            int xj = kb * 2 + (ko >> 5);
            int yj = ko & 31;
            #pragma unroll
            for (int j = 0; j < 4; ++j) {
                int dx = xi[j] - xj; dx = dx < 0 ? -dx : dx;
                int dy = yi[j] - yj; dy = dy < 0 ? -dy : dy;
                p[cf][j] = s[cf][j] + biasrow[dx * 32 + dy];
            }
        }
        #pragma unroll
        for (int j = 0; j < 4; ++j) {
            float rm = fmaxf(fmaxf(p[0][j], p[1][j]), fmaxf(p[2][j], p[3][j]));
            rm = fmaxf(rm, __shfl_xor(rm, 1));
            rm = fmaxf(rm, __shfl_xor(rm, 2));
            rm = fmaxf(rm, __shfl_xor(rm, 4));
            rm = fmaxf(rm, __shfl_xor(rm, 8));
            float nm = fmaxf(m[j], rm);
            float al = __expf(m[j] - nm);
            float rs = 0.f;
            #pragma unroll
            for (int cf = 0; cf < 4; ++cf) { p[cf][j] = __expf(p[cf][j] - nm); rs += p[cf][j]; }
            rs += __shfl_xor(rs, 1);
            rs += __shfl_xor(rs, 2);
            rs += __shfl_xor(rs, 4);
            rs += __shfl_xor(rs, 8);
            lsum[j] = lsum[j] * al + rs;
            m[j] = nm;
            #pragma unroll
            for (int cf = 0; cf < 4; ++cf) acc[cf][j] *= al;
        }

        // P -> per-wave LDS (bf16, XOR-swizzled rows); DS ops are wave-in-order
        #pragma unroll
        for (int j = 0; j < 4; ++j) {
            int qrl = lg * 4 + j;
            int rxor = (qrl & 7) << 4;
            #pragma unroll
            for (int cf = 0; cf < 4; ++cf) {
                int kbyte = (cf * 32 + l15 * 2) ^ rxor;
                *(unsigned short*)((char*)Pls + w * 2048 + qrl * 128 + kbyte) = f2b(p[cf][j]);
            }
        }
        __asm__ volatile("s_waitcnt lgkmcnt(0)" ::: "memory");

        // PV: A-frag = P rows, B-frag = V^T rows from swizzled LDS
        #pragma unroll
        for (int ks = 0; ks < 2; ++ks) {
            const bf16x8 pa = *(const bf16x8*)((char*)Pls + w * 2048 + l15 * 128 +
                                               ((ks * 64 + lg * 16) ^ ((l15 & 7) << 4)));
            #pragma unroll
            for (int cf = 0; cf < 4; ++cf) {
                int vd = cf * 16 + l15;
                const bf16x8 vb = *(const bf16x8*)((char*)Vls + vd * 128 +
                                                   ((ks * 64 + lg * 16) ^ ((vd & 7) << 4)));
                acc[cf] = __builtin_amdgcn_mfma_f32_16x16x32_bf16(pa, vb, acc[cf], 0, 0, 0);
            }
        }
    }

    // epilogue: normalize, hardswish, hi/lo split into augmented activations
    #pragma unroll
    for (int cf = 0; cf < 4; ++cf)
    #pragma unroll
    for (int j = 0; j < 4; ++j) {
        float ov = acc[cf][j] / lsum[j];
        float hs = ov * fminf(fmaxf(ov + 3.f, 0.f), 6.f) * (1.f / 6.f);
        unsigned short hi = f2b(hs);
        unsigned short lo = f2b(hs - b2f(hi));
        size_t tok = (size_t)b * 1024 + qb * 64 + w * 16 + lg * 4 + j;
        int c = h * 64 + cf * 16 + l15;
        Oaug[tok * 1536 + c]        = hi;
        Oaug[tok * 1536 + 512 + c]  = hi;
        Oaug[tok * 1536 + 1024 + c] = lo;
    }
}

// ---------------------------------------------------------------------------
extern "C" void kernel_launch(void* const* d_in, const int* in_sizes, int n_in,
                              void* d_out, int out_size, void* d_ws, size_t ws_size,
                              hipStream_t stream)
{
    const float* x   = (const float*)d_in[0];
    const float* qw  = (const float*)d_in[1];
    const float* qg  = (const float*)d_in[2];
    const float* qbe = (const float*)d_in[3];
    const float* qmu = (const float*)d_in[4];
    const float* qva = (const float*)d_in[5];
    const float* pw  = (const float*)d_in[6];
    const float* pg  = (const float*)d_in[7];
    const float* pbe = (const float*)d_in[8];
    const float* pmu = (const float*)d_in[9];
    const float* pva = (const float*)d_in[10];
    const float* ab  = (const float*)d_in[11];
    // d_in[12] (bias_idxs) replicated arithmetically in-kernel

    char* ws = (char*)d_ws;
    size_t off = 0;
    auto alloc = [&](size_t bytes) {
        size_t o = off; off = (off + bytes + 255) & ~(size_t)255; return o;
    };

    size_t region0 = alloc((size_t)16384 * 1536 * 2); // x_bf16 (early) / Oaug (late)
    size_t o_wT  = alloc((size_t)1024 * 384 * 2);
    size_t o_pwT = alloc((size_t)384 * 1536 * 2);
    size_t o_t1  = alloc(1024 * 4);
    size_t o_t2  = alloc(384 * 4);
    size_t o_q   = alloc((size_t)16 * 8 * 1024 * 32 * 2);
    size_t o_k   = alloc((size_t)16 * 8 * 1024 * 32 * 2);
    size_t o_v   = alloc((size_t)16 * 8 * 1024 * 64 * 2);
    size_t o_vt  = alloc((size_t)16 * 8 * 1024 * 64 * 2);

    unsigned short* xb   = (unsigned short*)(ws + region0);
    unsigned short* Oaug = (unsigned short*)(ws + region0);
    unsigned short* wT   = (unsigned short*)(ws + o_wT);
    unsigned short* pwT  = (unsigned short*)(ws + o_pwT);
    float* t1 = (float*)(ws + o_t1);
    float* t2 = (float*)(ws + o_t2);
    unsigned short* qb_ = (unsigned short*)(ws + o_q);
    unsigned short* kb_ = (unsigned short*)(ws + o_k);
    unsigned short* vb_ = (unsigned short*)(ws + o_v);
    unsigned short* vtb = (unsigned short*)(ws + o_vt);

    prep_w_qkv<<<1536, 256, 0, stream>>>(qw, qg, qbe, qmu, qva, wT, t1);
    prep_w_proj<<<768, 256, 0, stream>>>(pw, pg, pbe, pmu, pva, pwT, t2);
    prep_x<<<24576, 256, 0, stream>>>(x, xb);

    gemm_bt<128, 128, 0><<<dim3(128, 8), 256, 0, stream>>>(
        xb, wT, 384, t1, qb_, kb_, vb_, nullptr);

    vtrans_kernel<<<dim3(128, 16), 256, 0, stream>>>(vb_, vtb);

    attn_kernel<<<dim3(16, 8, 16), 256, 0, stream>>>(qb_, kb_, vtb, ab, Oaug);

    gemm_bt<64, 128, 1><<<dim3(256, 3), 256, 0, stream>>>(
        Oaug, pwT, 1536, t2, nullptr, nullptr, nullptr, (float*)d_out);
}